// Round 9
// baseline (103.014 us; speedup 1.0000x reference)
//
#include <hip/hip_runtime.h>
#include <hip/hip_bf16.h>

typedef __bf16 bf16x8 __attribute__((ext_vector_type(8)));
typedef float  f32x4  __attribute__((ext_vector_type(4)));

#define NSEG   39
#define NCAT   26
#define NCTS   13
#define VOCAB  100000
#define DIM    64
#define HID    512
#define KTOT   2496   // 39*64
#define MT     64     // rows per block
#define RD     6      // gather ring depth

// K-step order: segs 26..38 (cts) first, then 0..25 (cat).
// seg(i) = i<13 ? 26+i : i-13

__global__ void w1_to_bf16(const float* __restrict__ w1, ushort* __restrict__ w1b, int n4) {
    int i = blockIdx.x * blockDim.x + threadIdx.x;
    if (i >= n4) return;
    f32x4 v = ((const f32x4*)w1)[i];
    ushort4 o;
    o.x = __builtin_bit_cast(unsigned short, (__bf16)v[0]);
    o.y = __builtin_bit_cast(unsigned short, (__bf16)v[1]);
    o.z = __builtin_bit_cast(unsigned short, (__bf16)v[2]);
    o.w = __builtin_bit_cast(unsigned short, (__bf16)v[3]);
    ((ushort4*)w1b)[i] = o;
}

template<bool W1BF>
__global__ __launch_bounds__(512, 1)
void fused_net(const float* __restrict__ x,      // B x 39
               const float* __restrict__ emb,    // 26 x V x 64
               const float* __restrict__ ctsW,   // 13 x 64
               const float* __restrict__ ctsB,   // 13 x 64
               const void*  __restrict__ W1p,    // 512 x 2496 (bf16 or f32)
               const float* __restrict__ b1,     // 512
               const float* __restrict__ W2,     // 512
               const float* __restrict__ b2,     // 1
               float* __restrict__ out)          // B
{
    const int tid  = threadIdx.x;
    const int lane = tid & 63;
    const int wave = tid >> 6;
    const int m0   = blockIdx.x * MT;

    __shared__ float xs[MT * NSEG];                      // 9984 B
    __shared__ float ctsw_s[NCTS * DIM];                 // 3328 B
    __shared__ float ctsb_s[NCTS * DIM];                 // 3328 B
    __shared__ __align__(16) ushort Abuf[2][MT * DIM];   // 2 x 8 KB bf16, swizzled
    __shared__ float hsum[MT];                           // 256 B

    // staging geometry: thread -> (row r, 16B slot s); content chunk c = s ^ (r&7)
    const int r = tid >> 3;
    const int s = tid & 7;
    const int c = s ^ (r & 7);

    // gather ring (depth 6), 32 B per thread per segment
    f32x4 g0[RD], g1[RD];

    // ---- earliest possible gathers: cat segs 0..5, indices straight from global x ----
#pragma unroll
    for (int c0 = 0; c0 < RD; ++c0) {
        int idx = (int)x[(size_t)(m0 + r) * NSEG + c0];
        const float* p = emb + ((size_t)c0 * VOCAB + (size_t)idx) * DIM + c * 8;
        g0[c0] = __builtin_nontemporal_load((const f32x4*)p);
        g1[c0] = __builtin_nontemporal_load(((const f32x4*)p) + 1);
    }

    for (int e = tid; e < MT * NSEG; e += 512)
        xs[e] = x[(size_t)m0 * NSEG + e];
    for (int e = tid; e < NCTS * DIM; e += 512) {
        ctsw_s[e] = ctsW[e];
        ctsb_s[e] = ctsB[e];
    }
    if (tid < MT) hsum[tid] = 0.f;
    __syncthreads();

    unsigned bbase[4];
#pragma unroll
    for (int ni = 0; ni < 4; ++ni)
        bbase[ni] = (unsigned)(wave * 64 + ni * 16 + (lane & 15)) * KTOT + ((lane >> 4) << 3);

    const ushort* W1b = (const ushort*)W1p;
    const float*  W1f = (const float*)W1p;

    auto issueG = [&](int t, int slot) {   // t = cat seg (indices now from xs)
        int idx = (int)xs[r * NSEG + t];
        const float* p = emb + ((size_t)t * VOCAB + (size_t)idx) * DIM + c * 8;
        g0[slot] = __builtin_nontemporal_load((const f32x4*)p);
        g1[slot] = __builtin_nontemporal_load(((const f32x4*)p) + 1);
    };

    auto writeA = [&](int seg, int slot, int buf) {
        float vv[8];
        if (seg < NCAT) {
#pragma unroll
            for (int k = 0; k < 4; ++k) { vv[k] = g0[slot][k]; vv[4 + k] = g1[slot][k]; }
            if (seg >= 1) {
#pragma unroll
                for (int k = 0; k < 8; ++k) vv[k] = fmaxf(vv[k], 0.f);
            }
        } else {
            int jj = seg - NCAT;
            float sx = xs[r * NSEG + seg];
            f32x4 w0 = *(const f32x4*)&ctsw_s[jj * DIM + c * 8];
            f32x4 w1 = *(const f32x4*)&ctsw_s[jj * DIM + c * 8 + 4];
            f32x4 q0 = *(const f32x4*)&ctsb_s[jj * DIM + c * 8];
            f32x4 q1 = *(const f32x4*)&ctsb_s[jj * DIM + c * 8 + 4];
#pragma unroll
            for (int k = 0; k < 4; ++k) {
                vv[k]     = fmaxf(fmaf(sx, w0[k], q0[k]), 0.f);
                vv[4 + k] = fmaxf(fmaf(sx, w1[k], q1[k]), 0.f);
            }
        }
        bf16x8 o;
#pragma unroll
        for (int k = 0; k < 8; ++k) o[k] = (__bf16)vv[k];
        *(bf16x8*)&Abuf[buf][r * DIM + s * 8] = o;
    };

    bf16x8 bfr[2][2][4];  // [set][ks][ni]
    auto loadB = [&](int t, int set) {   // t = seg number (K-offset t*64)
#pragma unroll
        for (int ks = 0; ks < 2; ++ks)
#pragma unroll
            for (int ni = 0; ni < 4; ++ni) {
                unsigned off = bbase[ni] + t * 64 + ks * 32;
                if constexpr (W1BF) {
                    bfr[set][ks][ni] = *(const bf16x8*)(W1b + off);
                } else {
                    f32x4 u0 = *(const f32x4*)(W1f + off);
                    f32x4 u1 = *(const f32x4*)(W1f + off + 4);
                    bf16x8 tmp;
#pragma unroll
                    for (int k = 0; k < 4; ++k) {
                        tmp[k]     = (__bf16)u0[k];
                        tmp[4 + k] = (__bf16)u1[k];
                    }
                    bfr[set][ks][ni] = tmp;
                }
            }
    };

    f32x4 acc[4][4];
#pragma unroll
    for (int mi = 0; mi < 4; ++mi)
#pragma unroll
        for (int ni = 0; ni < 4; ++ni)
            acc[mi][ni] = (f32x4){0.f, 0.f, 0.f, 0.f};

    // prologue: first B set + stage seg(0)=26 (cts) into buf 0
    loadB(26, 0);
    writeA(26, 0, 0);
    asm volatile("s_waitcnt lgkmcnt(0)" ::: "memory");
    __builtin_amdgcn_s_barrier();
    __builtin_amdgcn_sched_barrier(0);

    // main loop: 39 steps; seg(i) = i<13 ? 26+i : i-13
    for (int ii = 0; ii < 42; ii += 6) {
#pragma unroll
        for (int j = 0; j < 6; ++j) {
            const int i = ii + j;
            if (i < NSEG) {
                const int s1 = (i + 1 < 13) ? 27 + i : i - 12;   // seg(i+1)

                if (i + 1 < NSEG) loadB(s1, (j + 1) & 1);
                // refill ring: cat seg c = i-7 into slot (i-7)%6 = (j+5)%6
                if (i >= 13 && i <= 32) issueG(i - 7, (j + 5) % 6);

#pragma unroll
                for (int ks = 0; ks < 2; ++ks) {
                    bf16x8 afr[4];
#pragma unroll
                    for (int mi = 0; mi < 4; ++mi) {
                        int R = mi * 16 + (lane & 15);
                        int C = ks * 4 + (lane >> 4);
                        afr[mi] = *(const bf16x8*)&Abuf[j & 1][R * DIM + ((C ^ (R & 7)) << 3)];
                    }
#pragma unroll
                    for (int ni = 0; ni < 4; ++ni)
#pragma unroll
                        for (int mi = 0; mi < 4; ++mi)
                            acc[mi][ni] = __builtin_amdgcn_mfma_f32_16x16x32_bf16(
                                afr[mi], bfr[j & 1][ks][ni], acc[mi][ni], 0, 0, 0);
                }

                // stage seg(i+1); ring slot for cat = (i+1-13)%6 = j
                if (i + 1 < NSEG) writeA(s1, j, (j & 1) ^ 1);

                asm volatile("s_waitcnt lgkmcnt(0)" ::: "memory");
                __builtin_amdgcn_s_barrier();
                __builtin_amdgcn_sched_barrier(0);
            }
        }
    }

    // epilogue: out = exp(relu(acc + b1) @ W2 + b2)
    float pv[4][4];
#pragma unroll
    for (int mi = 0; mi < 4; ++mi)
#pragma unroll
        for (int rg = 0; rg < 4; ++rg) pv[mi][rg] = 0.f;

#pragma unroll
    for (int ni = 0; ni < 4; ++ni) {
        int n = wave * 64 + ni * 16 + (lane & 15);
        float b1v = b1[n];
        float w2v = W2[n];
#pragma unroll
        for (int mi = 0; mi < 4; ++mi)
#pragma unroll
            for (int rg = 0; rg < 4; ++rg) {
                float h = fmaxf(acc[mi][ni][rg] + b1v, 0.f);
                pv[mi][rg] = fmaf(h, w2v, pv[mi][rg]);
            }
    }

#pragma unroll
    for (int m = 1; m < 16; m <<= 1)
#pragma unroll
        for (int mi = 0; mi < 4; ++mi)
#pragma unroll
            for (int rg = 0; rg < 4; ++rg)
                pv[mi][rg] += __shfl_xor(pv[mi][rg], m, 64);

    if ((lane & 15) == 0) {
        int rq = lane >> 4;
#pragma unroll
        for (int mi = 0; mi < 4; ++mi)
#pragma unroll
            for (int rg = 0; rg < 4; ++rg)
                atomicAdd(&hsum[mi * 16 + rq * 4 + rg], pv[mi][rg]);
    }
    __syncthreads();

    if (tid < MT) out[m0 + tid] = expf(hsum[tid] + b2[0]);
}

extern "C" void kernel_launch(void* const* d_in, const int* in_sizes, int n_in,
                              void* d_out, int out_size, void* d_ws, size_t ws_size,
                              hipStream_t stream) {
    const float* x    = (const float*)d_in[0];
    const float* emb  = (const float*)d_in[1];
    const float* ctsW = (const float*)d_in[2];
    const float* ctsB = (const float*)d_in[3];
    const float* W1   = (const float*)d_in[4];
    const float* b1   = (const float*)d_in[5];
    const float* W2   = (const float*)d_in[6];
    const float* b2   = (const float*)d_in[7];
    float* out = (float*)d_out;

    const int Bn   = in_sizes[0] / NSEG;         // 16384
    const int nblk = Bn / MT;                    // 256
    const size_t w1b_bytes = (size_t)HID * KTOT * sizeof(unsigned short);

    if (ws_size >= w1b_bytes) {
        ushort* W1b = (ushort*)d_ws;
        int n4 = HID * KTOT / 4;
        w1_to_bf16<<<(n4 + 255) / 256, 256, 0, stream>>>(W1, W1b, n4);
        fused_net<true><<<nblk, 512, 0, stream>>>(x, emb, ctsW, ctsB, (const void*)W1b,
                                                  b1, W2, b2, out);
    } else {
        fused_net<false><<<nblk, 512, 0, stream>>>(x, emb, ctsW, ctsB, (const void*)W1,
                                                   b1, W2, b2, out);
    }
}

// Round 10
// 89.496 us; speedup vs baseline: 1.1511x; 1.1511x over previous
//
#include <hip/hip_runtime.h>
#include <hip/hip_bf16.h>

typedef __bf16 bf16x8 __attribute__((ext_vector_type(8)));
typedef float  f32x4  __attribute__((ext_vector_type(4)));

#define NSEG   39
#define NCAT   26
#define NCTS   13
#define VOCAB  100000
#define DIM    64
#define HID    512
#define KTOT   2496   // 39*64
#define MT     64     // rows per block

// K-step ORDER (only change vs the 94.5 µs champion): 2 cat : 1 cts interleave
//   group g=0..12: cat 2g, cat 2g+1, cts 26+g
// so embedding gathers issue across the whole loop instead of the first 23 steps.

__global__ void w1_to_bf16(const float* __restrict__ w1, ushort* __restrict__ w1b, int n4) {
    int i = blockIdx.x * blockDim.x + threadIdx.x;
    if (i >= n4) return;
    f32x4 v = ((const f32x4*)w1)[i];
    ushort4 o;
    o.x = __builtin_bit_cast(unsigned short, (__bf16)v[0]);
    o.y = __builtin_bit_cast(unsigned short, (__bf16)v[1]);
    o.z = __builtin_bit_cast(unsigned short, (__bf16)v[2]);
    o.w = __builtin_bit_cast(unsigned short, (__bf16)v[3]);
    ((ushort4*)w1b)[i] = o;
}

template<bool W1BF>
__global__ __launch_bounds__(512, 1)
void fused_net(const float* __restrict__ x,      // B x 39
               const float* __restrict__ emb,    // 26 x V x 64
               const float* __restrict__ ctsW,   // 13 x 64
               const float* __restrict__ ctsB,   // 13 x 64
               const void*  __restrict__ W1p,    // 512 x 2496 (bf16 or f32)
               const float* __restrict__ b1,     // 512
               const float* __restrict__ W2,     // 512
               const float* __restrict__ b2,     // 1
               float* __restrict__ out)          // B
{
    const int tid  = threadIdx.x;
    const int lane = tid & 63;
    const int wave = tid >> 6;
    const int m0   = blockIdx.x * MT;

    __shared__ float xs[MT * NSEG];                      // 9984 B
    __shared__ float ctsw_s[NCTS * DIM];                 // 3328 B
    __shared__ float ctsb_s[NCTS * DIM];                 // 3328 B
    __shared__ __align__(16) ushort Abuf[2][MT * DIM];   // 2 x 8 KB bf16, swizzled
    __shared__ float hsum[MT];                           // 256 B

    for (int e = tid; e < MT * NSEG; e += 512)
        xs[e] = x[(size_t)m0 * NSEG + e];
    for (int e = tid; e < NCTS * DIM; e += 512) {
        ctsw_s[e] = ctsW[e];
        ctsb_s[e] = ctsB[e];
    }
    if (tid < MT) hsum[tid] = 0.f;
    __syncthreads();

    // staging: thread -> (row r, 16B slot s); content chunk c = s ^ (r&7)
    const int r = tid >> 3;
    const int s = tid & 7;
    const int c = s ^ (r & 7);

    unsigned bbase[4];
#pragma unroll
    for (int ni = 0; ni < 4; ++ni)
        bbase[ni] = (unsigned)(wave * 64 + ni * 16 + (lane & 15)) * KTOT + ((lane >> 4) << 3);

    const ushort* W1b = (const ushort*)W1p;
    const float*  W1f = (const float*)W1p;

    // gather ring, depth 4 (slot = catseg & 3), 32 B per thread per segment
    f32x4 g0[4], g1[4];

    auto issueG = [&](int t, int slot) {
        int idx = (int)xs[r * NSEG + t];
        const float* p = emb + ((size_t)t * VOCAB + (size_t)idx) * DIM + c * 8;
        g0[slot] = *(const f32x4*)p;
        g1[slot] = *(const f32x4*)(p + 4);
    };

    auto writeA = [&](int seg, int slot, int buf, bool isCat) {
        float vv[8];
        if (isCat) {
#pragma unroll
            for (int k = 0; k < 4; ++k) { vv[k] = g0[slot][k]; vv[4 + k] = g1[slot][k]; }
            if (seg >= 1) {
#pragma unroll
                for (int k = 0; k < 8; ++k) vv[k] = fmaxf(vv[k], 0.f);
            }
        } else {
            int jj = seg - NCAT;
            float sx = xs[r * NSEG + seg];
            f32x4 w0 = *(const f32x4*)&ctsw_s[jj * DIM + c * 8];
            f32x4 w1 = *(const f32x4*)&ctsw_s[jj * DIM + c * 8 + 4];
            f32x4 q0 = *(const f32x4*)&ctsb_s[jj * DIM + c * 8];
            f32x4 q1 = *(const f32x4*)&ctsb_s[jj * DIM + c * 8 + 4];
#pragma unroll
            for (int k = 0; k < 4; ++k) {
                vv[k]     = fmaxf(fmaf(sx, w0[k], q0[k]), 0.f);
                vv[4 + k] = fmaxf(fmaf(sx, w1[k], q1[k]), 0.f);
            }
        }
        bf16x8 o;
#pragma unroll
        for (int k = 0; k < 8; ++k) o[k] = (__bf16)vv[k];
        *(bf16x8*)&Abuf[buf][r * DIM + s * 8] = o;
    };

    bf16x8 bfr[2][2][4];  // [set][ks][ni]
    auto loadB = [&](int t, int set) {   // t = seg number -> W1 K-slice t*64
#pragma unroll
        for (int ks = 0; ks < 2; ++ks)
#pragma unroll
            for (int ni = 0; ni < 4; ++ni) {
                unsigned off = bbase[ni] + t * 64 + ks * 32;
                if constexpr (W1BF) {
                    bfr[set][ks][ni] = *(const bf16x8*)(W1b + off);
                } else {
                    f32x4 u0 = *(const f32x4*)(W1f + off);
                    f32x4 u1 = *(const f32x4*)(W1f + off + 4);
                    bf16x8 tmp;
#pragma unroll
                    for (int k = 0; k < 4; ++k) {
                        tmp[k]     = (__bf16)u0[k];
                        tmp[4 + k] = (__bf16)u1[k];
                    }
                    bfr[set][ks][ni] = tmp;
                }
            }
    };

    f32x4 acc[4][4];
#pragma unroll
    for (int mi = 0; mi < 4; ++mi)
#pragma unroll
        for (int ni = 0; ni < 4; ++ni)
            acc[mi][ni] = (f32x4){0.f, 0.f, 0.f, 0.f};

    auto mmaStep = [&](int buf, int set) {
#pragma unroll
        for (int ks = 0; ks < 2; ++ks) {
            bf16x8 afr[4];
#pragma unroll
            for (int mi = 0; mi < 4; ++mi) {
                int R = mi * 16 + (lane & 15);
                int C = ks * 4 + (lane >> 4);
                afr[mi] = *(const bf16x8*)&Abuf[buf][R * DIM + ((C ^ (R & 7)) << 3)];
            }
#pragma unroll
            for (int ni = 0; ni < 4; ++ni)
#pragma unroll
                for (int mi = 0; mi < 4; ++mi)
                    acc[mi][ni] = __builtin_amdgcn_mfma_f32_16x16x32_bf16(
                        afr[mi], bfr[set][ks][ni], acc[mi][ni], 0, 0, 0);
        }
    };

    // one K-step: stage seg -> barrier -> {loadB next, refill ring, MFMA}
#define STEP(SEG, SLOT, BUF, SET, NEXTSEG, NEXTSET, ISSC, ISCAT) do {          \
        writeA((SEG), (SLOT), (BUF), (ISCAT));                                 \
        asm volatile("s_waitcnt lgkmcnt(0)" ::: "memory");                     \
        __builtin_amdgcn_s_barrier();                                          \
        __builtin_amdgcn_sched_barrier(0);                                     \
        if ((NEXTSEG) >= 0) loadB((NEXTSEG), (NEXTSET));                       \
        if ((ISSC) >= 0 && (ISSC) < NCAT) issueG((ISSC), (ISSC) & 3);          \
        mmaStep((BUF), (SET));                                                 \
    } while (0)

    // prologue: ring cats 0..3, first B set (seg 0)
    issueG(0, 0); issueG(1, 1); issueG(2, 2); issueG(3, 3);
    loadB(0, 0);

    // main loop: 12 groups of (cat,cat,cts) x 2 per iteration; cats c0..c0+3, cts u0,u0+1
    for (int m = 0; m < 6; ++m) {
        const int c0 = 4 * m;
        const int u0 = 26 + 2 * m;
        STEP(c0,     0, 0, 0, c0 + 1, 1, c0 + 4, true);
        STEP(c0 + 1, 1, 1, 1, u0,     0, c0 + 5, true);
        STEP(u0,     0, 0, 0, c0 + 2, 1, -1,     false);
        STEP(c0 + 2, 2, 1, 1, c0 + 3, 0, c0 + 6, true);
        STEP(c0 + 3, 3, 0, 0, u0 + 1, 1, c0 + 7, true);
        STEP(u0 + 1, 0, 1, 1, c0 + 4, 0, -1,     false);
    }
    // tail group g=12: cats 24,25, cts 38
    STEP(24, 0, 0, 0, 25, 1, -1, true);
    STEP(25, 1, 1, 1, 38, 0, -1, true);
    STEP(38, 0, 0, 0, -1, 0, -1, false);
#undef STEP

    // epilogue: out = exp(relu(acc + b1) @ W2 + b2)
    float pv[4][4];
#pragma unroll
    for (int mi = 0; mi < 4; ++mi)
#pragma unroll
        for (int rg = 0; rg < 4; ++rg) pv[mi][rg] = 0.f;

#pragma unroll
    for (int ni = 0; ni < 4; ++ni) {
        int n = wave * 64 + ni * 16 + (lane & 15);
        float b1v = b1[n];
        float w2v = W2[n];
#pragma unroll
        for (int mi = 0; mi < 4; ++mi)
#pragma unroll
            for (int rg = 0; rg < 4; ++rg) {
                float h = fmaxf(acc[mi][ni][rg] + b1v, 0.f);
                pv[mi][rg] = fmaf(h, w2v, pv[mi][rg]);
            }
    }

#pragma unroll
    for (int m = 1; m < 16; m <<= 1)
#pragma unroll
        for (int mi = 0; mi < 4; ++mi)
#pragma unroll
            for (int rg = 0; rg < 4; ++rg)
                pv[mi][rg] += __shfl_xor(pv[mi][rg], m, 64);

    if ((lane & 15) == 0) {
        int rq = lane >> 4;
#pragma unroll
        for (int mi = 0; mi < 4; ++mi)
#pragma unroll
            for (int rg = 0; rg < 4; ++rg)
                atomicAdd(&hsum[mi * 16 + rq * 4 + rg], pv[mi][rg]);
    }
    __syncthreads();

    if (tid < MT) out[m0 + tid] = expf(hsum[tid] + b2[0]);
}

extern "C" void kernel_launch(void* const* d_in, const int* in_sizes, int n_in,
                              void* d_out, int out_size, void* d_ws, size_t ws_size,
                              hipStream_t stream) {
    const float* x    = (const float*)d_in[0];
    const float* emb  = (const float*)d_in[1];
    const float* ctsW = (const float*)d_in[2];
    const float* ctsB = (const float*)d_in[3];
    const float* W1   = (const float*)d_in[4];
    const float* b1   = (const float*)d_in[5];
    const float* W2   = (const float*)d_in[6];
    const float* b2   = (const float*)d_in[7];
    float* out = (float*)d_out;

    const int Bn   = in_sizes[0] / NSEG;         // 16384
    const int nblk = Bn / MT;                    // 256
    const size_t w1b_bytes = (size_t)HID * KTOT * sizeof(unsigned short);

    if (ws_size >= w1b_bytes) {
        ushort* W1b = (ushort*)d_ws;
        int n4 = HID * KTOT / 4;
        w1_to_bf16<<<(n4 + 255) / 256, 256, 0, stream>>>(W1, W1b, n4);
        fused_net<true><<<nblk, 512, 0, stream>>>(x, emb, ctsW, ctsB, (const void*)W1b,
                                                  b1, W2, b2, out);
    } else {
        fused_net<false><<<nblk, 512, 0, stream>>>(x, emb, ctsW, ctsB, (const void*)W1,
                                                   b1, W2, b2, out);
    }
}